// Round 8
// baseline (92.283 us; speedup 1.0000x reference)
//
#include <hip/hip_runtime.h>
#include <math.h>

#define N_RAYS 262144
#define N_SPHERES 256

__global__ __launch_bounds__(256) void ray_sphere_kernel(
    const float* __restrict__ ro,   // (N,3)
    const float* __restrict__ rd,   // (N,3)
    const float* __restrict__ sc,   // (M,3)
    const float* __restrict__ sr,   // (M,)
    float* __restrict__ out)        // 8N floats: t_hit | idx | hit_points | hit_normals
{
    __shared__ float4 sph[N_SPHERES];  // x,y,z = center, w = |c|^2 - r^2

    const int tid = threadIdx.x;
    {
        const float cx = sc[3 * tid + 0];
        const float cy = sc[3 * tid + 1];
        const float cz = sc[3 * tid + 2];
        const float r  = sr[tid];
        sph[tid] = make_float4(cx, cy, cz,
                               fmaf(cz, cz, fmaf(cy, cy, cx * cx)) - r * r);
    }
    __syncthreads();

    const int i = blockIdx.x * blockDim.x + tid;

    const float ox = ro[3 * i + 0], oy = ro[3 * i + 1], oz = ro[3 * i + 2];
    const float dx = rd[3 * i + 0], dy = rd[3 * i + 1], dz = rd[3 * i + 2];

    const float a    = fmaf(dz, dz, fmaf(dy, dy, dx * dx));
    const float nd   = -fmaf(dz, oz, fmaf(dy, oy, dx * ox));   // m = d.c - d.o
    const float on2  = fmaf(oz, oz, fmaf(oy, oy, ox * ox));
    const float inva = 1.0f / a;
    const float px = -2.0f * ox, py = -2.0f * oy, pz = -2.0f * oz;

    // u-space min (u = a*t): monotone in t since a > 0.
    float best_u = INFINITY;
    int   best_j = 0;  // argmin of all-inf row is 0 (matches jnp.argmin)

    // Group-of-4 ballot (amortizes the v_cmp->s_cbranch hazard 4x) with
    // FRESH loads each group and compiler-scheduled unroll-2 — no manual
    // register rotation (round 7's 16 v_mov/group mistake).
    // Per-sphere disc math bit-identical to the round-3 passing kernel.
    #pragma unroll 2
    for (int j = 0; j < N_SPHERES; j += 4) {
        const float4 c0 = sph[j + 0];
        const float4 c1 = sph[j + 1];
        const float4 c2 = sph[j + 2];
        const float4 c3 = sph[j + 3];

        const float m0 = fmaf(dz, c0.z, fmaf(dy, c0.y, fmaf(dx, c0.x, nd)));
        const float q0 = fmaf(pz, c0.z, fmaf(py, c0.y, fmaf(px, c0.x, on2 + c0.w)));
        const float d0 = fmaf(m0, m0, -(a * q0));
        const float m1 = fmaf(dz, c1.z, fmaf(dy, c1.y, fmaf(dx, c1.x, nd)));
        const float q1 = fmaf(pz, c1.z, fmaf(py, c1.y, fmaf(px, c1.x, on2 + c1.w)));
        const float d1 = fmaf(m1, m1, -(a * q1));
        const float m2 = fmaf(dz, c2.z, fmaf(dy, c2.y, fmaf(dx, c2.x, nd)));
        const float q2 = fmaf(pz, c2.z, fmaf(py, c2.y, fmaf(px, c2.x, on2 + c2.w)));
        const float d2 = fmaf(m2, m2, -(a * q2));
        const float m3 = fmaf(dz, c3.z, fmaf(dy, c3.y, fmaf(dx, c3.x, nd)));
        const float q3 = fmaf(pz, c3.z, fmaf(py, c3.y, fmaf(px, c3.x, on2 + c3.w)));
        const float d3 = fmaf(m3, m3, -(a * q3));

        // any lane, any of 4 spheres with a real root? (inputs finite -> no NaN)
        const float dmax = fmaxf(fmaxf(d0, d1), fmaxf(d2, d3));
        if (__ballot(dmax >= 0.0f) != 0ull) {
            // disc<0 lanes: sq=NaN -> u=NaN -> compares false -> no update.
            {
                const float sq = __builtin_amdgcn_sqrtf(d0);
                const float u1 = m0 - sq, u2 = m0 + sq;
                const float u  = (u1 > 0.0f) ? u1 : u2;
                if (u > 0.0f && u < best_u) { best_u = u; best_j = j + 0; }
            }
            {
                const float sq = __builtin_amdgcn_sqrtf(d1);
                const float u1 = m1 - sq, u2 = m1 + sq;
                const float u  = (u1 > 0.0f) ? u1 : u2;
                if (u > 0.0f && u < best_u) { best_u = u; best_j = j + 1; }
            }
            {
                const float sq = __builtin_amdgcn_sqrtf(d2);
                const float u1 = m2 - sq, u2 = m2 + sq;
                const float u  = (u1 > 0.0f) ? u1 : u2;
                if (u > 0.0f && u < best_u) { best_u = u; best_j = j + 2; }
            }
            {
                const float sq = __builtin_amdgcn_sqrtf(d3);
                const float u1 = m3 - sq, u2 = m3 + sq;
                const float u  = (u1 > 0.0f) ? u1 : u2;
                if (u > 0.0f && u < best_u) { best_u = u; best_j = j + 3; }
            }
        }
    }

    const float best_t = best_u * inva;
    const bool any_hit = isfinite(best_t);

    const float hx = fmaf(best_t, dx, ox);
    const float hy = fmaf(best_t, dy, oy);
    const float hz = fmaf(best_t, dz, oz);

    const float4 cs = sph[any_hit ? best_j : 0];
    float nx = hx - cs.x, ny = hy - cs.y, nz = hz - cs.z;
    const float inv_nrm = __builtin_amdgcn_rsqf(fmaf(nz, nz, fmaf(ny, ny, nx * nx)));
    nx *= inv_nrm; ny *= inv_nrm; nz *= inv_nrm;
    if (!any_hit) { nx = 0.0f; ny = 0.0f; nz = 0.0f; }

    // outputs: t_hit [0,N) | sphere_idx [N,2N) | hit_points [2N,5N) | normals [5N,8N)
    out[i]            = best_t;
    out[N_RAYS + i]   = any_hit ? (float)best_j : -1.0f;
    float* hp = out + 2 * N_RAYS;
    hp[3 * i + 0] = hx; hp[3 * i + 1] = hy; hp[3 * i + 2] = hz;
    float* hn = out + 5 * N_RAYS;
    hn[3 * i + 0] = nx; hn[3 * i + 1] = ny; hn[3 * i + 2] = nz;
}

extern "C" void kernel_launch(void* const* d_in, const int* in_sizes, int n_in,
                              void* d_out, int out_size, void* d_ws, size_t ws_size,
                              hipStream_t stream) {
    const float* ro = (const float*)d_in[0];
    const float* rd = (const float*)d_in[1];
    const float* sc = (const float*)d_in[2];
    const float* sr = (const float*)d_in[3];
    float* out = (float*)d_out;

    ray_sphere_kernel<<<N_RAYS / 256, 256, 0, stream>>>(ro, rd, sc, sr, out);
}